// Round 8
// baseline (152.238 us; speedup 1.0000x reference)
//
#include <hip/hip_runtime.h>
#include <hip/hip_bf16.h>

// Problem constants (match reference)
constexpr int F_ = 16;        // N_FEATURES
constexpr int K_ = 8;         // NUM_INSTANCES
constexpr int B_ = 16;        // batch
constexpr int HW_ = 512 * 512;
constexpr float DELTA_V = 0.5f;
constexpr float TWO_DELTA_D = 3.0f;   // 2 * 1.5
constexpr float GAMMA = 0.001f;

constexpr int CHUNKS = 64;            // chunks per image
constexpr int PIX = HW_ / CHUNKS;     // 4096 pixels per chunk
constexpr int SLOT = 136;             // per-block partial: 128 sums + 8 counts
constexpr int NPART = B_ * CHUNKS;    // 1024 blocks

// workspace layout (in floats)
constexpr int OFF_PART = 0;                          // NPART*SLOT
constexpr int OFF_IMG  = OFF_PART + NPART * SLOT;    // B*2 (ldist, lreg per image)
constexpr int OFF_LVAR = OFF_IMG + 2 * B_;           // B floats  (memset to 0)
constexpr int OFF_DONE = OFF_LVAR + B_;              // 1 u32     (memset to 0)

__device__ inline float waveReduceSum(float v) {
#pragma unroll
  for (int off = 32; off > 0; off >>= 1)
    v += __shfl_down(v, off, 64);
  return v;
}

__device__ inline float comp(const float4& v, int i) {
  return i == 0 ? v.x : i == 1 ? v.y : i == 2 ? v.z : v.w;
}

// Pass 1: per-(image,chunk) partial counts + feature sums -> ws slots (no atomics).
// grid (CHUNKS, B), block (64, 4): wave wy owns features [4*wy, 4*wy+4)
__global__ __launch_bounds__(256) void k1_sums(const float* __restrict__ pred,
                                               const int* __restrict__ tgt,
                                               float* __restrict__ ws) {
  float* part = ws + OFF_PART;
  const int b = blockIdx.y;
  const int chunk = blockIdx.x;
  const int lane = threadIdx.x;   // 0..63
  const int wy = threadIdx.y;     // 0..3

  float acc[4][8];
#pragma unroll
  for (int j = 0; j < 4; ++j)
#pragma unroll
    for (int k = 0; k < 8; ++k) acc[j][k] = 0.f;
  float cnt[8];
#pragma unroll
  for (int k = 0; k < 8; ++k) cnt[k] = 0.f;

  const int* tb = tgt + b * HW_ + chunk * PIX;
  const float* pb = pred + (size_t)b * F_ * HW_ + chunk * PIX;

  constexpr int ITERS = PIX / 256;  // 16 (64 lanes x 4 pixels per iter)
#pragma unroll 1
  for (int it = 0; it < ITERS; ++it) {
    const int p = it * 256 + lane * 4;
    const int4 lb = *reinterpret_cast<const int4*>(tb + p);
    float4 xr[4];
#pragma unroll
    for (int j = 0; j < 4; ++j)
      xr[j] = *reinterpret_cast<const float4*>(pb + (wy * 4 + j) * HW_ + p);

    const int labs[4] = {lb.x, lb.y, lb.z, lb.w};
    float sel[4][8];
#pragma unroll
    for (int pp = 0; pp < 4; ++pp)
#pragma unroll
      for (int k = 0; k < 8; ++k) sel[pp][k] = (labs[pp] == k) ? 1.f : 0.f;

#pragma unroll
    for (int j = 0; j < 4; ++j) {
#pragma unroll
      for (int k = 0; k < 8; ++k) {
        acc[j][k] = fmaf(sel[0][k], xr[j].x, acc[j][k]);
        acc[j][k] = fmaf(sel[1][k], xr[j].y, acc[j][k]);
        acc[j][k] = fmaf(sel[2][k], xr[j].z, acc[j][k]);
        acc[j][k] = fmaf(sel[3][k], xr[j].w, acc[j][k]);
      }
    }
    if (wy == 0) {
#pragma unroll
      for (int k = 0; k < 8; ++k)
        cnt[k] += sel[0][k] + sel[1][k] + sel[2][k] + sel[3][k];
    }
  }

  float* slot = part + (size_t)(b * CHUNKS + chunk) * SLOT;
#pragma unroll
  for (int j = 0; j < 4; ++j)
#pragma unroll
    for (int k = 0; k < 8; ++k) {
      float v = waveReduceSum(acc[j][k]);
      if (lane == 0) slot[k * F_ + wy * 4 + j] = v;
    }
  if (wy == 0) {
#pragma unroll
    for (int k = 0; k < 8; ++k) {
      float v = waveReduceSum(cnt[k]);
      if (lane == 0) slot[128 + k] = v;
    }
  }
}

// Pass 2: per-block mu prologue + l_var + tail finalize. grid (CHUNKS, B), block 256.
__global__ __launch_bounds__(256) void k3_lvar(const float* __restrict__ pred,
                                               const int* __restrict__ tgt,
                                               float* __restrict__ ws,
                                               float* __restrict__ out) {
  const float* part = ws + OFF_PART;
  float* img  = ws + OFF_IMG;
  float* lvar = ws + OFF_LVAR;
  unsigned* done = (unsigned*)(ws + OFF_DONE);
  const int b = blockIdx.y, chunk = blockIdx.x;
  const int t = threadIdx.x;

  __shared__ float tot[SLOT];
  __shared__ alignas(16) float mu_s[8][20];  // 80B rows: 16B aligned, banks spread
  __shared__ float inv_s[8];
  __shared__ float red[4];

  // ---- Prologue: every block reduces its image's 64 partial slots -> mu, inv ----
  if (t < SLOT) {
    float s = 0.f;
    const float* p = part + (size_t)b * CHUNKS * SLOT + t;
#pragma unroll 8
    for (int c = 0; c < CHUNKS; ++c) s += p[(size_t)c * SLOT];
    tot[t] = s;
  }
  __syncthreads();
  if (t < 8) inv_s[t] = 1.f / fmaxf(tot[128 + t], 1.f);
  __syncthreads();
  if (t < 128) mu_s[t >> 4][t & 15] = tot[t] * inv_s[t >> 4];
  __syncthreads();

  // ---- Only chunk-0 block computes l_dist + l_reg for this image ----
  if (chunk == 0) {
    __shared__ float lreg_arr[8];
    if (t < 8) {
      float s = 0.f;
#pragma unroll
      for (int f = 0; f < 16; ++f) s = fmaf(mu_s[t][f], mu_s[t][f], s);
      lreg_arr[t] = sqrtf(s);
    }
    if (t < 64) {
      int a = t >> 3, c2 = t & 7;
      float v = 0.f;
      if (a != c2) {
        float dsq = 0.f;
#pragma unroll
        for (int f = 0; f < 16; ++f) {
          float dd = mu_s[a][f] - mu_s[c2][f];
          dsq = fmaf(dd, dd, dsq);
        }
        float h = fmaxf(TWO_DELTA_D - sqrtf(dsq), 0.f);
        v = h * h;
      }
      v = waveReduceSum(v);
      if (t == 0) img[b * 2 + 0] = v;
    }
    __syncthreads();
    if (t == 0) {
      float lr = 0.f;
#pragma unroll
      for (int k = 0; k < 8; ++k) lr += lreg_arr[k];
      img[b * 2 + 1] = lr;
    }
  }

  // ---- Main: l_var over this chunk (reversed; 16 loads hoisted) ----
  const int* tb = tgt + b * HW_ + chunk * PIX;
  const float* pb = pred + (size_t)b * F_ * HW_ + chunk * PIX;

  float lsum = 0.f;
  constexpr int ITERS = PIX / 1024;  // 4 (256 threads x 4 pixels)
#pragma unroll 1
  for (int it = ITERS - 1; it >= 0; --it) {
    const int p = it * 1024 + t * 4;
    const int4 lb = *reinterpret_cast<const int4*>(tb + p);
    float4 xr[16];
#pragma unroll
    for (int f = 0; f < 16; ++f)
      xr[f] = *reinterpret_cast<const float4*>(pb + f * HW_ + p);

    const int labs[4] = {lb.x, lb.y, lb.z, lb.w};
    float d2[4] = {0.f, 0.f, 0.f, 0.f};
#pragma unroll
    for (int pp = 0; pp < 4; ++pp) {
      const float* mrow = &mu_s[labs[pp]][0];
#pragma unroll
      for (int f4 = 0; f4 < 4; ++f4) {
        const float4 m = *reinterpret_cast<const float4*>(mrow + f4 * 4);
        float e0 = comp(xr[f4 * 4 + 0], pp) - m.x;
        float e1 = comp(xr[f4 * 4 + 1], pp) - m.y;
        float e2 = comp(xr[f4 * 4 + 2], pp) - m.z;
        float e3 = comp(xr[f4 * 4 + 3], pp) - m.w;
        float s = fmaf(e0, e0, 0.f);
        s = fmaf(e1, e1, s);
        s = fmaf(e2, e2, s);
        s = fmaf(e3, e3, s);
        d2[pp] += s;
      }
    }
#pragma unroll
    for (int pp = 0; pp < 4; ++pp) {
      float dist = sqrtf(d2[pp]);
      float h = fmaxf(dist - DELTA_V, 0.f);
      lsum = fmaf(h * h, inv_s[labs[pp]], lsum);
    }
  }
  float v = waveReduceSum(lsum);
  const int lane = t & 63, wid = t >> 6;
  if (lane == 0) red[wid] = v;
  __syncthreads();

  // ---- Tail: accumulate lvar; 1024th arriver finalizes out ----
  if (t == 0) {
    atomicAdd(&lvar[b], red[0] + red[1] + red[2] + red[3]);
    unsigned d = __hip_atomic_fetch_add(done, 1u, __ATOMIC_ACQ_REL,
                                        __HIP_MEMORY_SCOPE_AGENT);
    if (d == (unsigned)(NPART - 1)) {
      float lv = 0.f, ld = 0.f, lr = 0.f;
#pragma unroll
      for (int bb = 0; bb < B_; ++bb) {
        lv += __hip_atomic_load(&lvar[bb], __ATOMIC_RELAXED, __HIP_MEMORY_SCOPE_AGENT);
        ld += __hip_atomic_load(&img[bb * 2 + 0], __ATOMIC_RELAXED, __HIP_MEMORY_SCOPE_AGENT);
        lr += __hip_atomic_load(&img[bb * 2 + 1], __ATOMIC_RELAXED, __HIP_MEMORY_SCOPE_AGENT);
      }
      lv *= 1.f / (K_ * (float)B_);
      ld *= 1.f / (K_ * (K_ - 1) * (float)B_);
      lr *= 1.f / (K_ * (float)B_);
      out[0] = lv + ld + GAMMA * lr;
      out[1] = lv;
      out[2] = ld;
      out[3] = lr;
    }
  }
}

extern "C" void kernel_launch(void* const* d_in, const int* in_sizes, int n_in,
                              void* d_out, int out_size, void* d_ws, size_t ws_size,
                              hipStream_t stream) {
  const float* pred = (const float*)d_in[0];
  const int* tgt = (const int*)d_in[1];
  float* out = (float*)d_out;
  float* ws = (float*)d_ws;

  // zero lvar[16] + done counter (contiguous: 16 floats + 1 u32 = 68 bytes)
  hipMemsetAsync(ws + OFF_LVAR, 0, (B_ + 1) * sizeof(float), stream);
  hipLaunchKernelGGL(k1_sums, dim3(CHUNKS, B_), dim3(64, 4), 0, stream, pred, tgt, ws);
  hipLaunchKernelGGL(k3_lvar, dim3(CHUNKS, B_), dim3(256), 0, stream, pred, tgt, ws, out);
}

// Round 9
// 130.732 us; speedup vs baseline: 1.1645x; 1.1645x over previous
//
#include <hip/hip_runtime.h>
#include <hip/hip_bf16.h>

// Problem constants (match reference)
constexpr int F_ = 16;        // N_FEATURES
constexpr int K_ = 8;         // NUM_INSTANCES
constexpr int B_ = 16;        // batch
constexpr int HW_ = 512 * 512;
constexpr float DELTA_V = 0.5f;
constexpr float TWO_DELTA_D = 3.0f;   // 2 * 1.5
constexpr float GAMMA = 0.001f;

constexpr int CHUNKS = 64;            // chunks per image
constexpr int PIX = HW_ / CHUNKS;     // 4096 pixels per chunk
constexpr int NBLK = B_ * CHUNKS;     // 1024 blocks = 4/CU x 256 CU (co-resident)
constexpr int SLOT = 136;             // per-image accum: 128 sums + 8 counts

// workspace layout (in floats)
constexpr int OFF_SUM  = 0;                      // B*SLOT   (relaxed atomicAdd targets)
constexpr int OFF_LVAR = OFF_SUM + B_ * SLOT;    // B
constexpr int OFF_IMG  = OFF_LVAR + B_;          // B*2 (ldist, lreg)
constexpr int OFF_MU   = OFF_IMG + 2 * B_;       // B*128
constexpr int OFF_INVC = OFF_MU + B_ * 128;      // B*8
constexpr int OFF_CTL  = OFF_INVC + B_ * K_;     // 513 u32: ctr[16*16], flag[16*16], done

__device__ inline float waveReduceSum(float v) {
#pragma unroll
  for (int off = 32; off > 0; off >>= 1)
    v += __shfl_down(v, off, 64);
  return v;
}

__device__ inline float comp(const float4& v, int i) {
  return i == 0 ? v.x : i == 1 ? v.y : i == 2 ? v.z : v.w;
}

// MALL-direct (cache-bypassing) relaxed atomic access — NO cache maintenance.
__device__ inline float dload(const float* p) {
  return __hip_atomic_load(p, __ATOMIC_RELAXED, __HIP_MEMORY_SCOPE_AGENT);
}
__device__ inline void dstore(float* p, float v) {
  __hip_atomic_store(p, v, __ATOMIC_RELAXED, __HIP_MEMORY_SCOPE_AGENT);
}
__device__ inline unsigned uload(const unsigned* p) {
  return __hip_atomic_load(p, __ATOMIC_RELAXED, __HIP_MEMORY_SCOPE_AGENT);
}

// Zero sums, lvar, control words (every call — harness doesn't re-poison).
__global__ void k0_init(float* __restrict__ ws) {
  const int t = threadIdx.x;
  for (int i = t; i < B_ * SLOT; i += 256) ws[OFF_SUM + i] = 0.f;
  if (t < B_) ws[OFF_LVAR + t] = 0.f;
  unsigned* ctl = (unsigned*)(ws + OFF_CTL);
  for (int i = t; i < 513; i += 256) ctl[i] = 0u;
}

__global__ __launch_bounds__(256, 4) void fused(const float* __restrict__ pred,
                                                const int* __restrict__ tgt,
                                                float* __restrict__ ws,
                                                float* __restrict__ out) {
  const int bid = blockIdx.x;
  const int b = bid >> 6, chunk = bid & 63;
  const int t = threadIdx.x;
  const int lane = t & 63, wy = t >> 6;

  float* sum_img = ws + OFF_SUM + b * SLOT;
  float* lvar = ws + OFF_LVAR;
  float* img  = ws + OFF_IMG;
  float* mu   = ws + OFF_MU;
  float* invc = ws + OFF_INVC;
  unsigned* ctl  = (unsigned*)(ws + OFF_CTL);
  unsigned* ctr  = ctl + b * 16;          // padded: one line per image
  unsigned* flag = ctl + 256 + b * 16;    // padded
  unsigned* done = ctl + 512;

  __shared__ alignas(16) float mu_s[8][20];  // 80B rows: 16B-aligned, banks spread
  __shared__ float inv_s[8];
  __shared__ float red[4];
  __shared__ int isred;

  const int* tb = tgt + b * HW_ + chunk * PIX;
  const float* pb = pred + (size_t)b * F_ * HW_ + chunk * PIX;

  // ---------------- Phase 1: partial sums/counts -> relaxed atomicAdd ---------------
  float acc[4][8];
#pragma unroll
  for (int j = 0; j < 4; ++j)
#pragma unroll
    for (int k = 0; k < 8; ++k) acc[j][k] = 0.f;
  float cnt[8];
#pragma unroll
  for (int k = 0; k < 8; ++k) cnt[k] = 0.f;

  constexpr int ITERS1 = PIX / 256;  // 16
#pragma unroll 1
  for (int it = 0; it < ITERS1; ++it) {
    const int p = it * 256 + lane * 4;
    const int4 lb = *reinterpret_cast<const int4*>(tb + p);
    float4 xr[4];
#pragma unroll
    for (int j = 0; j < 4; ++j)
      xr[j] = *reinterpret_cast<const float4*>(pb + (wy * 4 + j) * HW_ + p);

    const int labs[4] = {lb.x, lb.y, lb.z, lb.w};
    float sel[4][8];
#pragma unroll
    for (int pp = 0; pp < 4; ++pp)
#pragma unroll
      for (int k = 0; k < 8; ++k) sel[pp][k] = (labs[pp] == k) ? 1.f : 0.f;

#pragma unroll
    for (int j = 0; j < 4; ++j) {
#pragma unroll
      for (int k = 0; k < 8; ++k) {
        acc[j][k] = fmaf(sel[0][k], xr[j].x, acc[j][k]);
        acc[j][k] = fmaf(sel[1][k], xr[j].y, acc[j][k]);
        acc[j][k] = fmaf(sel[2][k], xr[j].z, acc[j][k]);
        acc[j][k] = fmaf(sel[3][k], xr[j].w, acc[j][k]);
      }
    }
    if (wy == 0) {
#pragma unroll
      for (int k = 0; k < 8; ++k)
        cnt[k] += sel[0][k] + sel[1][k] + sel[2][k] + sel[3][k];
    }
  }

#pragma unroll
  for (int j = 0; j < 4; ++j)
#pragma unroll
    for (int k = 0; k < 8; ++k) {
      float v = waveReduceSum(acc[j][k]);
      if (lane == 0) atomicAdd(&sum_img[k * F_ + wy * 4 + j], v);  // relaxed, device-routed
    }
  if (wy == 0) {
#pragma unroll
    for (int k = 0; k < 8; ++k) {
      float v = waveReduceSum(cnt[k]);
      if (lane == 0) atomicAdd(&sum_img[128 + k], v);
    }
  }
  // __syncthreads drains each wave's vmcnt -> all this block's RMWs are complete.
  __syncthreads();

  // ---------------- Arrival: 64th block of this image becomes reducer (RELAXED) -----
  if (t == 0) {
    asm volatile("s_waitcnt vmcnt(0)" ::: "memory");
    unsigned old = __hip_atomic_fetch_add(ctr, 1u, __ATOMIC_RELAXED,
                                          __HIP_MEMORY_SCOPE_AGENT);
    isred = (old == (unsigned)(CHUNKS - 1));
  }
  __syncthreads();

  if (isred) {
    __shared__ float tot[SLOT];
    __shared__ float lreg_sh[8];
    if (t < SLOT) tot[t] = dload(&sum_img[t]);
    __syncthreads();
    if (t < 8) {
      float iv = 1.f / fmaxf(tot[128 + t], 1.f);
      inv_s[t] = iv;
      dstore(&invc[b * K_ + t], iv);
    }
    __syncthreads();
    if (t < 128) {
      int k = t >> 4, f = t & 15;
      float m = tot[t] * inv_s[k];
      dstore(&mu[b * 128 + t], m);
      mu_s[k][f] = m;
    }
    __syncthreads();
    if (t < 8) {
      float s = 0.f;
#pragma unroll
      for (int f = 0; f < 16; ++f) s = fmaf(mu_s[t][f], mu_s[t][f], s);
      lreg_sh[t] = sqrtf(s);
    }
    if (t < 64) {  // l_dist pairs
      int a = t >> 3, c2 = t & 7;
      float v = 0.f;
      if (a != c2) {
        float dsq = 0.f;
#pragma unroll
        for (int f = 0; f < 16; ++f) {
          float dd = mu_s[a][f] - mu_s[c2][f];
          dsq = fmaf(dd, dd, dsq);
        }
        float h = fmaxf(TWO_DELTA_D - sqrtf(dsq), 0.f);
        v = h * h;
      }
      v = waveReduceSum(v);
      if (t == 0) dstore(&img[b * 2 + 0], v);
    }
    __syncthreads();
    if (t == 0) {
      float lr = 0.f;
#pragma unroll
      for (int k = 0; k < 8; ++k) lr += lreg_sh[k];
      dstore(&img[b * 2 + 1], lr);
      // all mu/invc/img dstores of other waves drained by the syncthreads above;
      // drain own, then signal (relaxed store, MALL-direct)
      asm volatile("s_waitcnt vmcnt(0)" ::: "memory");
      __hip_atomic_store(flag, 1u, __ATOMIC_RELAXED, __HIP_MEMORY_SCOPE_AGENT);
    }
  }

  // ---------------- Spin (relaxed bypass polls; no cache ops) -----------------------
  if (t == 0) {
    while (uload(flag) == 0u) __builtin_amdgcn_s_sleep(8);
  }
  __syncthreads();   // orders subsequent dloads after spin exit for all threads

  // ---------------- Phase 2: l_var over the SAME chunk (MALL-warm), reversed --------
  if (t < 128) mu_s[t >> 4][t & 15] = dload(&mu[b * 128 + t]);
  if (t < 8) inv_s[t] = dload(&invc[b * K_ + t]);
  __syncthreads();

  float lsum = 0.f;
  constexpr int ITERS2 = PIX / 1024;  // 4
#pragma unroll 1
  for (int it = ITERS2 - 1; it >= 0; --it) {
    const int p = it * 1024 + t * 4;
    const int4 lb = *reinterpret_cast<const int4*>(tb + p);
    float4 xr[16];
#pragma unroll
    for (int f = 0; f < 16; ++f)
      xr[f] = *reinterpret_cast<const float4*>(pb + f * HW_ + p);

    const int labs[4] = {lb.x, lb.y, lb.z, lb.w};
    float d2[4] = {0.f, 0.f, 0.f, 0.f};
#pragma unroll
    for (int pp = 0; pp < 4; ++pp) {
      const float* mrow = &mu_s[labs[pp]][0];
#pragma unroll
      for (int f4 = 0; f4 < 4; ++f4) {
        const float4 m = *reinterpret_cast<const float4*>(mrow + f4 * 4);
        float e0 = comp(xr[f4 * 4 + 0], pp) - m.x;
        float e1 = comp(xr[f4 * 4 + 1], pp) - m.y;
        float e2 = comp(xr[f4 * 4 + 2], pp) - m.z;
        float e3 = comp(xr[f4 * 4 + 3], pp) - m.w;
        float s = fmaf(e0, e0, 0.f);
        s = fmaf(e1, e1, s);
        s = fmaf(e2, e2, s);
        s = fmaf(e3, e3, s);
        d2[pp] += s;
      }
    }
#pragma unroll
    for (int pp = 0; pp < 4; ++pp) {
      float dist = sqrtf(d2[pp]);
      float h = fmaxf(dist - DELTA_V, 0.f);
      lsum = fmaf(h * h, inv_s[labs[pp]], lsum);
    }
  }
  float v = waveReduceSum(lsum);
  if (lane == 0) red[wy] = v;
  __syncthreads();

  // ---------------- Tail: relaxed lvar add; 1024th arriver finalizes ----------------
  if (t == 0) {
    atomicAdd(&lvar[b], red[0] + red[1] + red[2] + red[3]);  // relaxed
    asm volatile("s_waitcnt vmcnt(0)" ::: "memory");
    unsigned d = __hip_atomic_fetch_add(done, 1u, __ATOMIC_RELAXED,
                                        __HIP_MEMORY_SCOPE_AGENT);
    asm volatile("" ::: "memory");
    if (d == (unsigned)(NBLK - 1)) {
      float lv = 0.f, ld = 0.f, lr = 0.f;
#pragma unroll
      for (int bb = 0; bb < B_; ++bb) {
        lv += dload(&lvar[bb]);
        ld += dload(&img[bb * 2 + 0]);
        lr += dload(&img[bb * 2 + 1]);
      }
      lv *= 1.f / (K_ * (float)B_);
      ld *= 1.f / (K_ * (K_ - 1) * (float)B_);
      lr *= 1.f / (K_ * (float)B_);
      out[0] = lv + ld + GAMMA * lr;
      out[1] = lv;
      out[2] = ld;
      out[3] = lr;
    }
  }
}

extern "C" void kernel_launch(void* const* d_in, const int* in_sizes, int n_in,
                              void* d_out, int out_size, void* d_ws, size_t ws_size,
                              hipStream_t stream) {
  const float* pred = (const float*)d_in[0];
  const int* tgt = (const int*)d_in[1];
  float* out = (float*)d_out;
  float* ws = (float*)d_ws;

  hipLaunchKernelGGL(k0_init, dim3(1), dim3(256), 0, stream, ws);
  hipLaunchKernelGGL(fused, dim3(NBLK), dim3(256), 0, stream, pred, tgt, ws, out);
}

// Round 10
// 103.860 us; speedup vs baseline: 1.4658x; 1.2587x over previous
//
#include <hip/hip_runtime.h>
#include <hip/hip_bf16.h>

// Problem constants (match reference)
constexpr int F_ = 16;        // N_FEATURES
constexpr int K_ = 8;         // NUM_INSTANCES
constexpr int B_ = 16;        // batch
constexpr int HW_ = 512 * 512;
constexpr float DELTA_V = 0.5f;
constexpr float TWO_DELTA_D = 3.0f;   // 2 * 1.5
constexpr float GAMMA = 0.001f;

constexpr int CHUNKS = 64;            // chunks per image
constexpr int PIX = HW_ / CHUNKS;     // 4096 pixels per chunk
constexpr int SLOT = 136;             // per-block partial: 128 sums + 8 counts
constexpr int NPART = B_ * CHUNKS;    // 1024 blocks

// workspace layout (in floats) — no region needs zero-init (all plain stores)
constexpr int OFF_PART  = 0;                          // NPART*SLOT
constexpr int OFF_IMG   = OFF_PART + NPART * SLOT;    // B*2 (ldist, lreg per image)
constexpr int OFF_LVARP = OFF_IMG + 2 * B_;           // NPART per-block lvar partials

__device__ inline float waveReduceSum(float v) {
#pragma unroll
  for (int off = 32; off > 0; off >>= 1)
    v += __shfl_down(v, off, 64);
  return v;
}

__device__ inline float comp(const float4& v, int i) {
  return i == 0 ? v.x : i == 1 ? v.y : i == 2 ? v.z : v.w;
}

// Pass 1: per-(image,chunk) partial counts + feature sums -> ws slots (no atomics).
// grid (CHUNKS, B), block (64, 4): wave wy owns features [4*wy, 4*wy+4)
__global__ __launch_bounds__(256) void k1_sums(const float* __restrict__ pred,
                                               const int* __restrict__ tgt,
                                               float* __restrict__ ws) {
  float* part = ws + OFF_PART;
  const int b = blockIdx.y;
  const int chunk = blockIdx.x;
  const int lane = threadIdx.x;   // 0..63
  const int wy = threadIdx.y;     // 0..3

  float acc[4][8];
#pragma unroll
  for (int j = 0; j < 4; ++j)
#pragma unroll
    for (int k = 0; k < 8; ++k) acc[j][k] = 0.f;
  float cnt[8];
#pragma unroll
  for (int k = 0; k < 8; ++k) cnt[k] = 0.f;

  const int* tb = tgt + b * HW_ + chunk * PIX;
  const float* pb = pred + (size_t)b * F_ * HW_ + chunk * PIX;

  constexpr int ITERS = PIX / 256;  // 16 (64 lanes x 4 pixels per iter)
#pragma unroll 1
  for (int it = 0; it < ITERS; ++it) {
    const int p = it * 256 + lane * 4;
    const int4 lb = *reinterpret_cast<const int4*>(tb + p);
    float4 xr[4];
#pragma unroll
    for (int j = 0; j < 4; ++j)
      xr[j] = *reinterpret_cast<const float4*>(pb + (wy * 4 + j) * HW_ + p);

    const int labs[4] = {lb.x, lb.y, lb.z, lb.w};
    float sel[4][8];
#pragma unroll
    for (int pp = 0; pp < 4; ++pp)
#pragma unroll
      for (int k = 0; k < 8; ++k) sel[pp][k] = (labs[pp] == k) ? 1.f : 0.f;

#pragma unroll
    for (int j = 0; j < 4; ++j) {
#pragma unroll
      for (int k = 0; k < 8; ++k) {
        acc[j][k] = fmaf(sel[0][k], xr[j].x, acc[j][k]);
        acc[j][k] = fmaf(sel[1][k], xr[j].y, acc[j][k]);
        acc[j][k] = fmaf(sel[2][k], xr[j].z, acc[j][k]);
        acc[j][k] = fmaf(sel[3][k], xr[j].w, acc[j][k]);
      }
    }
    if (wy == 0) {
#pragma unroll
      for (int k = 0; k < 8; ++k)
        cnt[k] += sel[0][k] + sel[1][k] + sel[2][k] + sel[3][k];
    }
  }

  float* slot = part + (size_t)(b * CHUNKS + chunk) * SLOT;
#pragma unroll
  for (int j = 0; j < 4; ++j)
#pragma unroll
    for (int k = 0; k < 8; ++k) {
      float v = waveReduceSum(acc[j][k]);
      if (lane == 0) slot[k * F_ + wy * 4 + j] = v;
    }
  if (wy == 0) {
#pragma unroll
    for (int k = 0; k < 8; ++k) {
      float v = waveReduceSum(cnt[k]);
      if (lane == 0) slot[128 + k] = v;
    }
  }
}

// Pass 2: per-block mu prologue (redundant, no sync) + l_var main loop.
// grid (CHUNKS, B), block 256. chunk-0 block also writes l_dist/l_reg for its image.
// Per-block lvar partial written to a distinct slot (no atomics anywhere).
__global__ __launch_bounds__(256) void k3_lvar(const float* __restrict__ pred,
                                               const int* __restrict__ tgt,
                                               float* __restrict__ ws) {
  const float* part = ws + OFF_PART;
  float* img   = ws + OFF_IMG;
  float* lvarp = ws + OFF_LVARP;
  const int b = blockIdx.y, chunk = blockIdx.x;
  const int t = threadIdx.x;

  __shared__ float tot[SLOT];
  __shared__ alignas(16) float mu_s[8][20];  // 80B rows: 16B aligned, banks spread
  __shared__ float inv_s[8];
  __shared__ float red[4];

  // ---- Prologue: reduce this image's 64 partial slots -> mu, inv (L2-served) ----
  if (t < SLOT) {
    float s = 0.f;
    const float* p = part + (size_t)b * CHUNKS * SLOT + t;
#pragma unroll 8
    for (int c = 0; c < CHUNKS; ++c) s += p[(size_t)c * SLOT];
    tot[t] = s;
  }
  __syncthreads();
  if (t < 8) inv_s[t] = 1.f / fmaxf(tot[128 + t], 1.f);
  __syncthreads();
  if (t < 128) mu_s[t >> 4][t & 15] = tot[t] * inv_s[t >> 4];
  __syncthreads();

  // ---- Only the chunk-0 block computes l_dist + l_reg for this image ----
  if (chunk == 0) {
    __shared__ float lreg_arr[8];
    if (t < 8) {
      float s = 0.f;
#pragma unroll
      for (int f = 0; f < 16; ++f) s = fmaf(mu_s[t][f], mu_s[t][f], s);
      lreg_arr[t] = sqrtf(s);
    }
    if (t < 64) {
      int a = t >> 3, c2 = t & 7;
      float v = 0.f;
      if (a != c2) {
        float dsq = 0.f;
#pragma unroll
        for (int f = 0; f < 16; ++f) {
          float dd = mu_s[a][f] - mu_s[c2][f];
          dsq = fmaf(dd, dd, dsq);
        }
        float h = fmaxf(TWO_DELTA_D - sqrtf(dsq), 0.f);
        v = h * h;
      }
      v = waveReduceSum(v);
      if (t == 0) img[b * 2 + 0] = v;
    }
    __syncthreads();
    if (t == 0) {
      float lr = 0.f;
#pragma unroll
      for (int k = 0; k < 8; ++k) lr += lreg_arr[k];
      img[b * 2 + 1] = lr;
    }
  }

  // ---- Main: l_var over this chunk (reversed; 16 loads hoisted) ----
  const int* tb = tgt + b * HW_ + chunk * PIX;
  const float* pb = pred + (size_t)b * F_ * HW_ + chunk * PIX;

  float lsum = 0.f;
  constexpr int ITERS = PIX / 1024;  // 4 (256 threads x 4 pixels)
#pragma unroll 1
  for (int it = ITERS - 1; it >= 0; --it) {
    const int p = it * 1024 + t * 4;
    const int4 lb = *reinterpret_cast<const int4*>(tb + p);
    float4 xr[16];
#pragma unroll
    for (int f = 0; f < 16; ++f)
      xr[f] = *reinterpret_cast<const float4*>(pb + f * HW_ + p);

    const int labs[4] = {lb.x, lb.y, lb.z, lb.w};
    float d2[4] = {0.f, 0.f, 0.f, 0.f};
#pragma unroll
    for (int pp = 0; pp < 4; ++pp) {
      const float* mrow = &mu_s[labs[pp]][0];
#pragma unroll
      for (int f4 = 0; f4 < 4; ++f4) {
        const float4 m = *reinterpret_cast<const float4*>(mrow + f4 * 4);
        float e0 = comp(xr[f4 * 4 + 0], pp) - m.x;
        float e1 = comp(xr[f4 * 4 + 1], pp) - m.y;
        float e2 = comp(xr[f4 * 4 + 2], pp) - m.z;
        float e3 = comp(xr[f4 * 4 + 3], pp) - m.w;
        float s = fmaf(e0, e0, 0.f);
        s = fmaf(e1, e1, s);
        s = fmaf(e2, e2, s);
        s = fmaf(e3, e3, s);
        d2[pp] += s;
      }
    }
#pragma unroll
    for (int pp = 0; pp < 4; ++pp) {
      float dist = sqrtf(d2[pp]);
      float h = fmaxf(dist - DELTA_V, 0.f);
      lsum = fmaf(h * h, inv_s[labs[pp]], lsum);
    }
  }
  float v = waveReduceSum(lsum);
  const int lane = t & 63, wid = t >> 6;
  if (lane == 0) red[wid] = v;
  __syncthreads();
  if (t == 0) lvarp[b * CHUNKS + chunk] = red[0] + red[1] + red[2] + red[3];
}

// Final: sum 1024 lvar partials + 16 (ldist,lreg) pairs -> out[4]. 1 block x 256.
__global__ __launch_bounds__(256) void k4_final(const float* __restrict__ ws,
                                                float* __restrict__ out) {
  const float* img = ws + OFF_IMG;
  const float* lvarp = ws + OFF_LVARP;
  const int t = threadIdx.x;
  __shared__ float red[4];
  __shared__ float ldlr[32];

  float s = 0.f;
#pragma unroll
  for (int j = 0; j < 4; ++j) s += lvarp[t * 4 + j];
  float v = waveReduceSum(s);
  const int lane = t & 63, wid = t >> 6;
  if (lane == 0) red[wid] = v;
  if (t < 32) ldlr[t] = img[t];
  __syncthreads();
  if (t == 0) {
    float lv = red[0] + red[1] + red[2] + red[3];
    float ld = 0.f, lr = 0.f;
#pragma unroll
    for (int bb = 0; bb < B_; ++bb) {
      ld += ldlr[bb * 2 + 0];
      lr += ldlr[bb * 2 + 1];
    }
    lv *= 1.f / (K_ * (float)B_);
    ld *= 1.f / (K_ * (K_ - 1) * (float)B_);
    lr *= 1.f / (K_ * (float)B_);
    out[0] = lv + ld + GAMMA * lr;
    out[1] = lv;
    out[2] = ld;
    out[3] = lr;
  }
}

extern "C" void kernel_launch(void* const* d_in, const int* in_sizes, int n_in,
                              void* d_out, int out_size, void* d_ws, size_t ws_size,
                              hipStream_t stream) {
  const float* pred = (const float*)d_in[0];
  const int* tgt = (const int*)d_in[1];
  float* out = (float*)d_out;
  float* ws = (float*)d_ws;

  hipLaunchKernelGGL(k1_sums, dim3(CHUNKS, B_), dim3(64, 4), 0, stream, pred, tgt, ws);
  hipLaunchKernelGGL(k3_lvar, dim3(CHUNKS, B_), dim3(256), 0, stream, pred, tgt, ws);
  hipLaunchKernelGGL(k4_final, dim3(1), dim3(256), 0, stream, ws, out);
}